// Round 1
// baseline (4151.666 us; speedup 1.0000x reference)
//
#include <hip/hip_runtime.h>
#include <hip/hip_bf16.h>
#include <math.h>

#define BS   4096
#define ZD   512
#define HIDN 1024
#define ZINN 128
#define NST  32

typedef unsigned short u16;
typedef __bf16 bf16x8 __attribute__((ext_vector_type(8)));
typedef float f32x4 __attribute__((ext_vector_type(4)));

static __device__ __forceinline__ u16 bf_bits(float v) {
  __bf16 b = (__bf16)v;
  return __builtin_bit_cast(unsigned short, b);
}
static __device__ __forceinline__ float bf_val(float v) {
  return (float)(__bf16)v;
}

// ---------------- prep kernels ----------------

// split f32 array into bf16 hi/lo pair
__global__ void k_split(const float* __restrict__ s, u16* __restrict__ hi,
                        u16* __restrict__ lo, int n) {
  int i = blockIdx.x * 256 + threadIdx.x;
  if (i >= n) return;
  float v = s[i];
  float h = bf_val(v);
  hi[i] = bf_bits(v);
  lo[i] = bf_bits(v - h);
}

// extract W_ih[:,3:131] -> split; W_ih[:,0:3] -> compact wtok; combined bias cb0
__global__ void k_prep_wih(const float* __restrict__ W_ih, const float* __restrict__ b_ih,
                           const float* __restrict__ b_hh,
                           u16* __restrict__ whi, u16* __restrict__ wlo,
                           float* __restrict__ wtok, float* __restrict__ cb0) {
  int i = blockIdx.x * 256 + threadIdx.x;
  if (i < 3072 * 128) {
    int r = i >> 7, c = i & 127;
    float v = W_ih[r * 131 + 3 + c];
    float h = bf_val(v);
    whi[i] = bf_bits(v);
    wlo[i] = bf_bits(v - h);
  }
  if (i < 3072 * 3) {
    int r = i / 3, c = i - r * 3;
    wtok[i] = W_ih[r * 131 + c];
  }
  if (i < 3072) {
    // b_ih everywhere; b_hh folded in for r,u chunks only (b_hh_n lives inside r*h_n)
    cb0[i] = b_ih[i] + (i < 2048 ? b_hh[i] : 0.0f);
  }
}

__global__ void k_token_init(const float* __restrict__ init_input, float* __restrict__ token) {
  int i = blockIdx.x * 256 + threadIdx.x;
  if (i < BS * 3) token[i] = init_input[i % 3];
}

// ---------------- split-3 bf16 MFMA GEMM:  C[M,N] = A[M,K] * B[N,K]^T (+bias) ----------------
// A,B given as bf16 hi/lo splits. 128x128 block tile, BK=64, 256 threads (4 waves, each 64x64).
// LDS rows padded to 72 shorts (144B, 16B-aligned) -> conflict-free ds_read_b128.
template <bool SPLIT_OUT>
__global__ __launch_bounds__(256) void k_gemm(
    const u16* __restrict__ Ahi, const u16* __restrict__ Alo,
    const u16* __restrict__ Bhi, const u16* __restrict__ Blo,
    const float* __restrict__ bias,
    float* __restrict__ C, u16* __restrict__ Chi, u16* __restrict__ Clo,
    int N, int K) {
  const int LDT = 72;
  __shared__ __align__(16) u16 sA[2][128 * LDT];
  __shared__ __align__(16) u16 sB[2][128 * LDT];

  const int t = threadIdx.x;
  const int row0 = blockIdx.y * 128, col0 = blockIdx.x * 128;
  const int wave = t >> 6, lane = t & 63;
  const int wm = (wave & 1) * 64, wn = (wave >> 1) * 64;
  const int lm = lane & 15, lq = lane >> 4;

  f32x4 acc[4][4] = {};

  const int sr = t >> 1;        // 0..127 : tile row (A) / tile col (B)
  const int sc = (t & 1) * 32;  // 0 or 32 : k-offset chunk

  const int nk = K >> 6;
  for (int kt = 0; kt < nk; ++kt) {
    const int k0 = kt << 6;
    __syncthreads();
    const u16* ga_hi = Ahi + (size_t)(row0 + sr) * K + k0 + sc;
    const u16* ga_lo = Alo + (size_t)(row0 + sr) * K + k0 + sc;
    const u16* gb_hi = Bhi + (size_t)(col0 + sr) * K + k0 + sc;
    const u16* gb_lo = Blo + (size_t)(col0 + sr) * K + k0 + sc;
    u16* la_hi = &sA[0][sr * LDT + sc];
    u16* la_lo = &sA[1][sr * LDT + sc];
    u16* lb_hi = &sB[0][sr * LDT + sc];
    u16* lb_lo = &sB[1][sr * LDT + sc];
#pragma unroll
    for (int c = 0; c < 4; ++c) {
      *(uint4*)(la_hi + 8 * c) = *(const uint4*)(ga_hi + 8 * c);
      *(uint4*)(la_lo + 8 * c) = *(const uint4*)(ga_lo + 8 * c);
      *(uint4*)(lb_hi + 8 * c) = *(const uint4*)(gb_hi + 8 * c);
      *(uint4*)(lb_lo + 8 * c) = *(const uint4*)(gb_lo + 8 * c);
    }
    __syncthreads();
#pragma unroll
    for (int kk = 0; kk < 2; ++kk) {
      const int ko = kk * 32 + lq * 8;
      bf16x8 ah[4], al[4], bh[4], bl[4];
#pragma unroll
      for (int i = 0; i < 4; ++i) {
        ah[i] = *(const bf16x8*)&sA[0][(wm + i * 16 + lm) * LDT + ko];
        al[i] = *(const bf16x8*)&sA[1][(wm + i * 16 + lm) * LDT + ko];
        bh[i] = *(const bf16x8*)&sB[0][(wn + i * 16 + lm) * LDT + ko];
        bl[i] = *(const bf16x8*)&sB[1][(wn + i * 16 + lm) * LDT + ko];
      }
#pragma unroll
      for (int i = 0; i < 4; ++i)
#pragma unroll
        for (int j = 0; j < 4; ++j) {
          acc[i][j] = __builtin_amdgcn_mfma_f32_16x16x32_bf16(ah[i], bh[j], acc[i][j], 0, 0, 0);
          acc[i][j] = __builtin_amdgcn_mfma_f32_16x16x32_bf16(al[i], bh[j], acc[i][j], 0, 0, 0);
          acc[i][j] = __builtin_amdgcn_mfma_f32_16x16x32_bf16(ah[i], bl[j], acc[i][j], 0, 0, 0);
        }
    }
  }

#pragma unroll
  for (int i = 0; i < 4; ++i) {
    const int grow = row0 + wm + i * 16 + lq * 4;
#pragma unroll
    for (int j = 0; j < 4; ++j) {
      const int gcol = col0 + wn + j * 16 + lm;
      const float bs = bias ? bias[gcol] : 0.0f;
#pragma unroll
      for (int d = 0; d < 4; ++d) {
        const float v = acc[i][j][d] + bs;
        const size_t idx = (size_t)(grow + d) * N + gcol;
        C[idx] = v;
        if (SPLIT_OUT) {
          const float h = bf_val(v);
          Chi[idx] = bf_bits(v);
          Clo[idx] = bf_bits(v - h);
        }
      }
    }
  }
}

// ---------------- per-step gate kernel ----------------
// pre = C0 + gh + token @ W_ih[:, :3]^T ; GRU gates in exact f32; writes h f32 + bf16 splits
__global__ __launch_bounds__(256) void k_gate(
    const float* __restrict__ C0, const float* __restrict__ gh,
    const float* __restrict__ token, const float* __restrict__ wtok,
    const float* __restrict__ b_hh,
    float* __restrict__ h, u16* __restrict__ h_hi, u16* __restrict__ h_lo) {
  const int i = blockIdx.x * 256 + threadIdx.x;  // over BS*HIDN
  const int row = i >> 10, col = i & 1023;
  const float t0 = token[row * 3 + 0];
  const float t1 = token[row * 3 + 1];
  const float t2 = token[row * 3 + 2];
  const size_t b = (size_t)row * 3072;
  const int cr = col, cu = 1024 + col, cn = 2048 + col;
  const float pr = C0[b + cr] + gh[b + cr] + t0 * wtok[cr * 3] + t1 * wtok[cr * 3 + 1] + t2 * wtok[cr * 3 + 2];
  const float pu = C0[b + cu] + gh[b + cu] + t0 * wtok[cu * 3] + t1 * wtok[cu * 3 + 1] + t2 * wtok[cu * 3 + 2];
  const float in_ = C0[b + cn] + t0 * wtok[cn * 3] + t1 * wtok[cn * 3 + 1] + t2 * wtok[cn * 3 + 2];
  const float hn = gh[b + cn] + b_hh[2048 + col];
  const float r = 1.0f / (1.0f + expf(-pr));
  const float u = 1.0f / (1.0f + expf(-pu));
  const float n = tanhf(in_ + r * hn);
  const float ho = h[i];
  const float hv = (1.0f - u) * n + u * ho;
  h[i] = hv;
  const float hh = bf_val(hv);
  h_hi[i] = bf_bits(hv);
  h_lo[i] = bf_bits(hv - hh);
}

// ---------------- per-step output kernel ----------------
// o = h @ W_out^T + b_out  (3 dots of K=1024 per row, one wave per row, f32)
__global__ __launch_bounds__(256) void k_out(
    const float* __restrict__ h, const float* __restrict__ W_out,
    const float* __restrict__ b_out,
    float* __restrict__ out, float* __restrict__ token, int step) {
  const int wave = threadIdx.x >> 6, lane = threadIdx.x & 63;
  const int row = blockIdx.x * 4 + wave;
  const float4* hp = (const float4*)(h + (size_t)row * 1024);
  const float4* w0p = (const float4*)(W_out);
  const float4* w1p = (const float4*)(W_out + 1024);
  const float4* w2p = (const float4*)(W_out + 2048);
  float s0 = 0.f, s1 = 0.f, s2 = 0.f;
#pragma unroll
  for (int c = 0; c < 4; ++c) {
    const int k = lane + 64 * c;
    const float4 hv = hp[k];
    const float4 a = w0p[k], bq = w1p[k], cq = w2p[k];
    s0 += hv.x * a.x + hv.y * a.y + hv.z * a.z + hv.w * a.w;
    s1 += hv.x * bq.x + hv.y * bq.y + hv.z * bq.z + hv.w * bq.w;
    s2 += hv.x * cq.x + hv.y * cq.y + hv.z * cq.z + hv.w * cq.w;
  }
#pragma unroll
  for (int off = 32; off > 0; off >>= 1) {
    s0 += __shfl_xor(s0, off, 64);
    s1 += __shfl_xor(s1, off, 64);
    s2 += __shfl_xor(s2, off, 64);
  }
  if (lane == 0) {
    const float o0 = s0 + b_out[0];
    const float o1 = s1 + b_out[1];
    const float o2 = s2 + b_out[2];
    const float bass = 1.0f / (1.0f + expf(-o0));
    const float rhy = 1.0f / (1.0f + expf(-o2));
    const size_t ob = ((size_t)row * NST + step) * 3;
    out[ob + 0] = bass;
    out[ob + 1] = o1;
    out[ob + 2] = rhy;
    token[row * 3 + 0] = bass;
    token[row * 3 + 1] = o1;
    token[row * 3 + 2] = (rhy > 0.5f) ? 1.0f : 0.0f;
  }
}

// ---------------- host ----------------
extern "C" void kernel_launch(void* const* d_in, const int* in_sizes, int n_in,
                              void* d_out, int out_size, void* d_ws, size_t ws_size,
                              hipStream_t stream) {
  const float* z = (const float*)d_in[0];
  const float* W_zh = (const float*)d_in[3];
  const float* b_zh = (const float*)d_in[4];
  const float* W_zi = (const float*)d_in[5];
  const float* b_zi = (const float*)d_in[6];
  const float* W_ih = (const float*)d_in[7];
  const float* b_ih = (const float*)d_in[8];
  const float* W_hh = (const float*)d_in[9];
  const float* b_hh = (const float*)d_in[10];
  const float* W_out = (const float*)d_in[11];
  const float* b_out = (const float*)d_in[12];
  const float* init_input = (const float*)d_in[13];
  float* out = (float*)d_out;

  char* p = (char*)d_ws;
  auto alloc = [&](size_t bytes) {
    char* q = p;
    p += (bytes + 255) & ~(size_t)255;
    return q;
  };
  float* h = (float*)alloc((size_t)BS * HIDN * 4);
  u16* h_hi = (u16*)alloc((size_t)BS * HIDN * 2);
  u16* h_lo = (u16*)alloc((size_t)BS * HIDN * 2);
  float* gh = (float*)alloc((size_t)BS * 3072 * 4);
  float* C0 = (float*)alloc((size_t)BS * 3072 * 4);
  u16* z_hi = (u16*)alloc((size_t)BS * ZD * 2);
  u16* z_lo = (u16*)alloc((size_t)BS * ZD * 2);
  float* zin = (float*)alloc((size_t)BS * ZINN * 4);
  u16* zin_hi = (u16*)alloc((size_t)BS * ZINN * 2);
  u16* zin_lo = (u16*)alloc((size_t)BS * ZINN * 2);
  u16* Wzh_hi = (u16*)alloc((size_t)HIDN * ZD * 2);
  u16* Wzh_lo = (u16*)alloc((size_t)HIDN * ZD * 2);
  u16* Wzi_hi = (u16*)alloc((size_t)ZINN * ZD * 2);
  u16* Wzi_lo = (u16*)alloc((size_t)ZINN * ZD * 2);
  u16* Wihz_hi = (u16*)alloc((size_t)3072 * ZINN * 2);
  u16* Wihz_lo = (u16*)alloc((size_t)3072 * ZINN * 2);
  u16* Whh_hi = (u16*)alloc((size_t)3072 * HIDN * 2);
  u16* Whh_lo = (u16*)alloc((size_t)3072 * HIDN * 2);
  float* wtok = (float*)alloc((size_t)3072 * 3 * 4);
  float* cb0 = (float*)alloc((size_t)3072 * 4);
  float* token = (float*)alloc((size_t)BS * 3 * 4);

  // ---- prep ----
  k_split<<<dim3((3072 * HIDN + 255) / 256), 256, 0, stream>>>(W_hh, Whh_hi, Whh_lo, 3072 * HIDN);
  k_split<<<dim3((HIDN * ZD + 255) / 256), 256, 0, stream>>>(W_zh, Wzh_hi, Wzh_lo, HIDN * ZD);
  k_split<<<dim3((ZINN * ZD + 255) / 256), 256, 0, stream>>>(W_zi, Wzi_hi, Wzi_lo, ZINN * ZD);
  k_split<<<dim3((BS * ZD + 255) / 256), 256, 0, stream>>>(z, z_hi, z_lo, BS * ZD);
  k_prep_wih<<<dim3((3072 * 128 + 255) / 256), 256, 0, stream>>>(W_ih, b_ih, b_hh, Wihz_hi, Wihz_lo, wtok, cb0);
  k_token_init<<<dim3((BS * 3 + 255) / 256), 256, 0, stream>>>(init_input, token);

  // ---- prep GEMMs ----
  // h0 = z @ W_zh^T + b_zh   (M=4096, N=1024, K=512), write f32 + splits
  k_gemm<true><<<dim3(HIDN / 128, BS / 128), 256, 0, stream>>>(
      z_hi, z_lo, Wzh_hi, Wzh_lo, b_zh, h, h_hi, h_lo, HIDN, ZD);
  // z_in = z @ W_zi^T + b_zi (M=4096, N=128, K=512)
  k_gemm<true><<<dim3(ZINN / 128, BS / 128), 256, 0, stream>>>(
      z_hi, z_lo, Wzi_hi, Wzi_lo, b_zi, zin, zin_hi, zin_lo, ZINN, ZD);
  // C0 = z_in @ Wihz^T + (b_ih [+ b_hh for r,u])  (M=4096, N=3072, K=128)
  k_gemm<false><<<dim3(3072 / 128, BS / 128), 256, 0, stream>>>(
      zin_hi, zin_lo, Wihz_hi, Wihz_lo, cb0, C0, nullptr, nullptr, 3072, ZINN);

  // ---- 32 recurrent steps ----
  for (int t = 0; t < NST; ++t) {
    // gh = h @ W_hh^T  (M=4096, N=3072, K=1024), no bias
    k_gemm<false><<<dim3(3072 / 128, BS / 128), 256, 0, stream>>>(
        h_hi, h_lo, Whh_hi, Whh_lo, nullptr, gh, nullptr, nullptr, 3072, HIDN);
    k_gate<<<dim3(BS * HIDN / 256), 256, 0, stream>>>(C0, gh, token, wtok, b_hh, h, h_hi, h_lo);
    k_out<<<dim3(BS / 4), 256, 0, stream>>>(h, W_out, b_out, out, token, t);
  }
  (void)in_sizes; (void)n_in; (void)out_size; (void)ws_size;
}

// Round 2
// 3335.766 us; speedup vs baseline: 1.2446x; 1.2446x over previous
//
#include <hip/hip_runtime.h>
#include <hip/hip_bf16.h>
#include <math.h>

#define BS   4096
#define ZD   512
#define HIDN 1024
#define ZINN 128
#define NST  32

typedef unsigned short u16;
typedef __bf16 bf16x8 __attribute__((ext_vector_type(8)));
typedef float f32x4 __attribute__((ext_vector_type(4)));

static __device__ __forceinline__ u16 bf_bits(float v) {
  __bf16 b = (__bf16)v;
  return __builtin_bit_cast(unsigned short, b);
}
static __device__ __forceinline__ float bf_val(float v) {
  return (float)(__bf16)v;
}

// async global -> LDS, 16 bytes per lane. LDS dest = wave-uniform base + lane*16.
static __device__ __forceinline__ void ld_lds16(const u16* g, u16* l) {
  __builtin_amdgcn_global_load_lds(
      (const __attribute__((address_space(1))) void*)g,
      (__attribute__((address_space(3))) void*)l, 16, 0, 0);
}

// ---------------- prep kernels ----------------

__global__ void k_split(const float* __restrict__ s, u16* __restrict__ hi,
                        u16* __restrict__ lo, int n) {
  int i = blockIdx.x * 256 + threadIdx.x;
  if (i >= n) return;
  float v = s[i];
  float h = bf_val(v);
  hi[i] = bf_bits(v);
  lo[i] = bf_bits(v - h);
}

__global__ void k_prep_wih(const float* __restrict__ W_ih, const float* __restrict__ b_ih,
                           const float* __restrict__ b_hh,
                           u16* __restrict__ whi, u16* __restrict__ wlo,
                           float* __restrict__ wtok, float* __restrict__ cb0) {
  int i = blockIdx.x * 256 + threadIdx.x;
  if (i < 3072 * 128) {
    int r = i >> 7, c = i & 127;
    float v = W_ih[r * 131 + 3 + c];
    float h = bf_val(v);
    whi[i] = bf_bits(v);
    wlo[i] = bf_bits(v - h);
  }
  if (i < 3072 * 3) {
    int r = i / 3, c = i - r * 3;
    wtok[i] = W_ih[r * 131 + c];
  }
  if (i < 3072) {
    cb0[i] = b_ih[i] + (i < 2048 ? b_hh[i] : 0.0f);
  }
}

__global__ void k_token_init(const float* __restrict__ init_input, float* __restrict__ token) {
  int i = blockIdx.x * 256 + threadIdx.x;
  if (i < BS * 3) token[i] = init_input[i % 3];
}

// ---------------- split-3 bf16 MFMA GEMM:  C[M,N] = A[M,K] * B[N,K]^T (+bias) ----------------
// 128x128 block tile, BK=64, 256 threads (4 waves, 64x64 each).
// Staging: global_load_lds 16B/lane into unpadded LDS [128][64] u16, with the
// k-chunk XOR-swizzled by (row&7) through the lane->element mapping so the
// ds_read_b128 fragment reads sit at the b128 bank floor (8 accesses/bank-group).
template <bool SPLIT_OUT>
__global__ __launch_bounds__(256) void k_gemm(
    const u16* __restrict__ Ahi, const u16* __restrict__ Alo,
    const u16* __restrict__ Bhi, const u16* __restrict__ Blo,
    const float* __restrict__ bias,
    float* __restrict__ C, u16* __restrict__ Chi, u16* __restrict__ Clo,
    int N, int K) {
  __shared__ __align__(16) u16 sAhi[128 * 64];
  __shared__ __align__(16) u16 sAlo[128 * 64];
  __shared__ __align__(16) u16 sBhi[128 * 64];
  __shared__ __align__(16) u16 sBlo[128 * 64];

  const int t = threadIdx.x;
  const int row0 = blockIdx.y * 128, col0 = blockIdx.x * 128;
  const int wave = t >> 6, lane = t & 63;
  const int w64 = wave * 64;
  const int wm = (wave & 1) * 64, wn = (wave >> 1) * 64;
  const int lm = lane & 15, lq = lane >> 4;
  const int pb = lm & 7;  // XOR swizzle base for fragment reads

  f32x4 acc[4][4] = {};

  // staging decomposition: unit u in [0,1024), u = m*8 + c; position c holds
  // global k-chunk kc = c ^ (m&7). Thread t, iter i handles u = i*256 + t;
  // wave-uniform LDS base unit = i*256 + w64.
  int sm[4], skc[4], sub[4];
#pragma unroll
  for (int i = 0; i < 4; ++i) {
    const int u = i * 256 + t;
    sm[i] = u >> 3;
    skc[i] = (u & 7) ^ (sm[i] & 7);
    sub[i] = (i * 256 + w64) * 8;
  }

  const int nk = K >> 6;
  for (int kt = 0; kt < nk; ++kt) {
    const int k0 = kt << 6;
    __syncthreads();
#pragma unroll
    for (int i = 0; i < 4; ++i) {
      const size_t ga = (size_t)(row0 + sm[i]) * K + k0 + skc[i] * 8;
      const size_t gb = (size_t)(col0 + sm[i]) * K + k0 + skc[i] * 8;
      ld_lds16(Ahi + ga, &sAhi[sub[i]]);
      ld_lds16(Alo + ga, &sAlo[sub[i]]);
      ld_lds16(Bhi + gb, &sBhi[sub[i]]);
      ld_lds16(Blo + gb, &sBlo[sub[i]]);
    }
    __syncthreads();
#pragma unroll
    for (int kk = 0; kk < 2; ++kk) {
      const int pos = ((kk * 4 + lq) ^ pb) * 8;
      bf16x8 ah[4], al[4], bh[4], bl[4];
#pragma unroll
      for (int i = 0; i < 4; ++i) {
        const int ma = (wm + i * 16 + lm) * 64;
        const int mb = (wn + i * 16 + lm) * 64;
        ah[i] = *(const bf16x8*)&sAhi[ma + pos];
        al[i] = *(const bf16x8*)&sAlo[ma + pos];
        bh[i] = *(const bf16x8*)&sBhi[mb + pos];
        bl[i] = *(const bf16x8*)&sBlo[mb + pos];
      }
#pragma unroll
      for (int i = 0; i < 4; ++i)
#pragma unroll
        for (int j = 0; j < 4; ++j) {
          acc[i][j] = __builtin_amdgcn_mfma_f32_16x16x32_bf16(ah[i], bh[j], acc[i][j], 0, 0, 0);
          acc[i][j] = __builtin_amdgcn_mfma_f32_16x16x32_bf16(al[i], bh[j], acc[i][j], 0, 0, 0);
          acc[i][j] = __builtin_amdgcn_mfma_f32_16x16x32_bf16(ah[i], bl[j], acc[i][j], 0, 0, 0);
        }
    }
  }

#pragma unroll
  for (int i = 0; i < 4; ++i) {
    const int grow = row0 + wm + i * 16 + lq * 4;
#pragma unroll
    for (int j = 0; j < 4; ++j) {
      const int gcol = col0 + wn + j * 16 + lm;
      const float bs = bias ? bias[gcol] : 0.0f;
#pragma unroll
      for (int d = 0; d < 4; ++d) {
        const float v = acc[i][j][d] + bs;
        const size_t idx = (size_t)(grow + d) * N + gcol;
        C[idx] = v;
        if (SPLIT_OUT) {
          const float h = bf_val(v);
          Chi[idx] = bf_bits(v);
          Clo[idx] = bf_bits(v - h);
        }
      }
    }
  }
}

// ---------------- per-step gate kernel ----------------
__global__ __launch_bounds__(256) void k_gate(
    const float* __restrict__ C0, const float* __restrict__ gh,
    const float* __restrict__ token, const float* __restrict__ wtok,
    const float* __restrict__ b_hh,
    float* __restrict__ h, u16* __restrict__ h_hi, u16* __restrict__ h_lo) {
  const int i = blockIdx.x * 256 + threadIdx.x;  // over BS*HIDN
  const int row = i >> 10, col = i & 1023;
  const float t0 = token[row * 3 + 0];
  const float t1 = token[row * 3 + 1];
  const float t2 = token[row * 3 + 2];
  const size_t b = (size_t)row * 3072;
  const int cr = col, cu = 1024 + col, cn = 2048 + col;
  const float pr = C0[b + cr] + gh[b + cr] + t0 * wtok[cr * 3] + t1 * wtok[cr * 3 + 1] + t2 * wtok[cr * 3 + 2];
  const float pu = C0[b + cu] + gh[b + cu] + t0 * wtok[cu * 3] + t1 * wtok[cu * 3 + 1] + t2 * wtok[cu * 3 + 2];
  const float in_ = C0[b + cn] + t0 * wtok[cn * 3] + t1 * wtok[cn * 3 + 1] + t2 * wtok[cn * 3 + 2];
  const float hn = gh[b + cn] + b_hh[2048 + col];
  const float r = 1.0f / (1.0f + expf(-pr));
  const float u = 1.0f / (1.0f + expf(-pu));
  const float n = tanhf(in_ + r * hn);
  const float ho = h[i];
  const float hv = (1.0f - u) * n + u * ho;
  h[i] = hv;
  const float hh = bf_val(hv);
  h_hi[i] = bf_bits(hv);
  h_lo[i] = bf_bits(hv - hh);
}

// ---------------- per-step output kernel ----------------
__global__ __launch_bounds__(256) void k_out(
    const float* __restrict__ h, const float* __restrict__ W_out,
    const float* __restrict__ b_out,
    float* __restrict__ out, float* __restrict__ token, int step) {
  const int wave = threadIdx.x >> 6, lane = threadIdx.x & 63;
  const int row = blockIdx.x * 4 + wave;
  const float4* hp = (const float4*)(h + (size_t)row * 1024);
  const float4* w0p = (const float4*)(W_out);
  const float4* w1p = (const float4*)(W_out + 1024);
  const float4* w2p = (const float4*)(W_out + 2048);
  float s0 = 0.f, s1 = 0.f, s2 = 0.f;
#pragma unroll
  for (int c = 0; c < 4; ++c) {
    const int k = lane + 64 * c;
    const float4 hv = hp[k];
    const float4 a = w0p[k], bq = w1p[k], cq = w2p[k];
    s0 += hv.x * a.x + hv.y * a.y + hv.z * a.z + hv.w * a.w;
    s1 += hv.x * bq.x + hv.y * bq.y + hv.z * bq.z + hv.w * bq.w;
    s2 += hv.x * cq.x + hv.y * cq.y + hv.z * cq.z + hv.w * cq.w;
  }
#pragma unroll
  for (int off = 32; off > 0; off >>= 1) {
    s0 += __shfl_xor(s0, off, 64);
    s1 += __shfl_xor(s1, off, 64);
    s2 += __shfl_xor(s2, off, 64);
  }
  if (lane == 0) {
    const float o0 = s0 + b_out[0];
    const float o1 = s1 + b_out[1];
    const float o2 = s2 + b_out[2];
    const float bass = 1.0f / (1.0f + expf(-o0));
    const float rhy = 1.0f / (1.0f + expf(-o2));
    const size_t ob = ((size_t)row * NST + step) * 3;
    out[ob + 0] = bass;
    out[ob + 1] = o1;
    out[ob + 2] = rhy;
    token[row * 3 + 0] = bass;
    token[row * 3 + 1] = o1;
    token[row * 3 + 2] = (rhy > 0.5f) ? 1.0f : 0.0f;
  }
}

// ---------------- host ----------------
extern "C" void kernel_launch(void* const* d_in, const int* in_sizes, int n_in,
                              void* d_out, int out_size, void* d_ws, size_t ws_size,
                              hipStream_t stream) {
  const float* z = (const float*)d_in[0];
  const float* W_zh = (const float*)d_in[3];
  const float* b_zh = (const float*)d_in[4];
  const float* W_zi = (const float*)d_in[5];
  const float* b_zi = (const float*)d_in[6];
  const float* W_ih = (const float*)d_in[7];
  const float* b_ih = (const float*)d_in[8];
  const float* W_hh = (const float*)d_in[9];
  const float* b_hh = (const float*)d_in[10];
  const float* W_out = (const float*)d_in[11];
  const float* b_out = (const float*)d_in[12];
  const float* init_input = (const float*)d_in[13];
  float* out = (float*)d_out;

  char* p = (char*)d_ws;
  auto alloc = [&](size_t bytes) {
    char* q = p;
    p += (bytes + 255) & ~(size_t)255;
    return q;
  };
  float* h = (float*)alloc((size_t)BS * HIDN * 4);
  u16* h_hi = (u16*)alloc((size_t)BS * HIDN * 2);
  u16* h_lo = (u16*)alloc((size_t)BS * HIDN * 2);
  float* gh = (float*)alloc((size_t)BS * 3072 * 4);
  float* C0 = (float*)alloc((size_t)BS * 3072 * 4);
  u16* z_hi = (u16*)alloc((size_t)BS * ZD * 2);
  u16* z_lo = (u16*)alloc((size_t)BS * ZD * 2);
  float* zin = (float*)alloc((size_t)BS * ZINN * 4);
  u16* zin_hi = (u16*)alloc((size_t)BS * ZINN * 2);
  u16* zin_lo = (u16*)alloc((size_t)BS * ZINN * 2);
  u16* Wzh_hi = (u16*)alloc((size_t)HIDN * ZD * 2);
  u16* Wzh_lo = (u16*)alloc((size_t)HIDN * ZD * 2);
  u16* Wzi_hi = (u16*)alloc((size_t)ZINN * ZD * 2);
  u16* Wzi_lo = (u16*)alloc((size_t)ZINN * ZD * 2);
  u16* Wihz_hi = (u16*)alloc((size_t)3072 * ZINN * 2);
  u16* Wihz_lo = (u16*)alloc((size_t)3072 * ZINN * 2);
  u16* Whh_hi = (u16*)alloc((size_t)3072 * HIDN * 2);
  u16* Whh_lo = (u16*)alloc((size_t)3072 * HIDN * 2);
  float* wtok = (float*)alloc((size_t)3072 * 3 * 4);
  float* cb0 = (float*)alloc((size_t)3072 * 4);
  float* token = (float*)alloc((size_t)BS * 3 * 4);

  // ---- prep ----
  k_split<<<dim3((3072 * HIDN + 255) / 256), 256, 0, stream>>>(W_hh, Whh_hi, Whh_lo, 3072 * HIDN);
  k_split<<<dim3((HIDN * ZD + 255) / 256), 256, 0, stream>>>(W_zh, Wzh_hi, Wzh_lo, HIDN * ZD);
  k_split<<<dim3((ZINN * ZD + 255) / 256), 256, 0, stream>>>(W_zi, Wzi_hi, Wzi_lo, ZINN * ZD);
  k_split<<<dim3((BS * ZD + 255) / 256), 256, 0, stream>>>(z, z_hi, z_lo, BS * ZD);
  k_prep_wih<<<dim3((3072 * 128 + 255) / 256), 256, 0, stream>>>(W_ih, b_ih, b_hh, Wihz_hi, Wihz_lo, wtok, cb0);
  k_token_init<<<dim3((BS * 3 + 255) / 256), 256, 0, stream>>>(init_input, token);

  // ---- prep GEMMs ----
  k_gemm<true><<<dim3(HIDN / 128, BS / 128), 256, 0, stream>>>(
      z_hi, z_lo, Wzh_hi, Wzh_lo, b_zh, h, h_hi, h_lo, HIDN, ZD);
  k_gemm<true><<<dim3(ZINN / 128, BS / 128), 256, 0, stream>>>(
      z_hi, z_lo, Wzi_hi, Wzi_lo, b_zi, zin, zin_hi, zin_lo, ZINN, ZD);
  k_gemm<false><<<dim3(3072 / 128, BS / 128), 256, 0, stream>>>(
      zin_hi, zin_lo, Wihz_hi, Wihz_lo, cb0, C0, nullptr, nullptr, 3072, ZINN);

  // ---- 32 recurrent steps ----
  for (int t = 0; t < NST; ++t) {
    k_gemm<false><<<dim3(3072 / 128, BS / 128), 256, 0, stream>>>(
        h_hi, h_lo, Whh_hi, Whh_lo, nullptr, gh, nullptr, nullptr, 3072, HIDN);
    k_gate<<<dim3(BS * HIDN / 256), 256, 0, stream>>>(C0, gh, token, wtok, b_hh, h, h_hi, h_lo);
    k_out<<<dim3(BS / 4), 256, 0, stream>>>(h, W_out, b_out, out, token, t);
  }
  (void)in_sizes; (void)n_in; (void)out_size; (void)ws_size;
}

// Round 3
// 3185.185 us; speedup vs baseline: 1.3034x; 1.0473x over previous
//
#include <hip/hip_runtime.h>
#include <hip/hip_bf16.h>
#include <math.h>

#define BS   4096
#define ZD   512
#define HIDN 1024
#define ZINN 128
#define NST  32
#define NP   3072   // 3*HIDN, gate-interleaved column space

typedef unsigned short u16;
typedef __bf16 bf16x8 __attribute__((ext_vector_type(8)));
typedef float f32x4 __attribute__((ext_vector_type(4)));

static __device__ __forceinline__ u16 bf_bits(float v) {
  __bf16 b = (__bf16)v;
  return __builtin_bit_cast(unsigned short, b);
}
static __device__ __forceinline__ float bf_val(float v) {
  return (float)(__bf16)v;
}

// async global -> LDS, 16 bytes per lane. LDS dest = wave-uniform base + lane*16.
static __device__ __forceinline__ void ld_lds16(const u16* g, u16* l) {
  __builtin_amdgcn_global_load_lds(
      (const __attribute__((address_space(1))) void*)g,
      (__attribute__((address_space(3))) void*)l, 16, 0, 0);
}

// W' row w -> original W_hh/W_ih row. w = g*48 + j*16 + m  ->  j*1024 + g*16 + m
static __device__ __forceinline__ int r_orig(int w) {
  const int g = w / 48;
  const int rem = w - g * 48;
  const int j = rem >> 4, m = rem & 15;
  return j * 1024 + g * 16 + m;
}

// ---------------- prep kernels ----------------

__global__ void k_split(const float* __restrict__ s, u16* __restrict__ hi,
                        u16* __restrict__ lo, int n) {
  int i = blockIdx.x * 256 + threadIdx.x;
  if (i >= n) return;
  float v = s[i];
  float h = bf_val(v);
  hi[i] = bf_bits(v);
  lo[i] = bf_bits(v - h);
}

// W_hh split with gate-interleaved row reorder
__global__ void k_split_whh(const float* __restrict__ W_hh, u16* __restrict__ hi,
                            u16* __restrict__ lo) {
  int i = blockIdx.x * 256 + threadIdx.x;
  if (i >= NP * HIDN) return;
  const int w = i >> 10, k = i & 1023;
  const float v = W_hh[(size_t)r_orig(w) * HIDN + k];
  const float h = bf_val(v);
  hi[i] = bf_bits(v);
  lo[i] = bf_bits(v - h);
}

// W_ih[:,3:131] -> split (reordered rows); W_ih[:,0:3] -> wtok (reordered); cb0 (reordered)
__global__ void k_prep_wih(const float* __restrict__ W_ih, const float* __restrict__ b_ih,
                           const float* __restrict__ b_hh,
                           u16* __restrict__ whi, u16* __restrict__ wlo,
                           float* __restrict__ wtok, float* __restrict__ cb0) {
  int i = blockIdx.x * 256 + threadIdx.x;
  if (i < NP * 128) {
    const int w = i >> 7, c = i & 127;
    const int r = r_orig(w);
    const float v = W_ih[r * 131 + 3 + c];
    const float h = bf_val(v);
    whi[i] = bf_bits(v);
    wlo[i] = bf_bits(v - h);
  }
  if (i < NP * 3) {
    const int w = i / 3, s = i - w * 3;
    wtok[i] = W_ih[r_orig(w) * 131 + s];
  }
  if (i < NP) {
    const int r = r_orig(i);
    cb0[i] = b_ih[r] + (r < 2048 ? b_hh[r] : 0.0f);
  }
}

__global__ void k_token_init(const float* __restrict__ init_input, float* __restrict__ token) {
  int i = blockIdx.x * 256 + threadIdx.x;
  if (i < BS * 4) token[i] = ((i & 3) < 3) ? init_input[i & 3] : 0.0f;
}

// ---------------- generic split-3 GEMM (prep only): C = A*B^T (+bias) ----------------
// Round-2 structure: 128x128 tile, BK=64, global_load_lds + XOR swizzle.
template <bool SPLIT_OUT>
__global__ __launch_bounds__(256) void k_gemm(
    const u16* __restrict__ Ahi, const u16* __restrict__ Alo,
    const u16* __restrict__ Bhi, const u16* __restrict__ Blo,
    const float* __restrict__ bias,
    float* __restrict__ C, u16* __restrict__ Chi, u16* __restrict__ Clo,
    int N, int K) {
  __shared__ __align__(16) u16 sAhi[128 * 64];
  __shared__ __align__(16) u16 sAlo[128 * 64];
  __shared__ __align__(16) u16 sBhi[128 * 64];
  __shared__ __align__(16) u16 sBlo[128 * 64];

  const int t = threadIdx.x;
  const int row0 = blockIdx.y * 128, col0 = blockIdx.x * 128;
  const int wave = t >> 6, lane = t & 63;
  const int w64 = wave * 64;
  const int wm = (wave & 1) * 64, wn = (wave >> 1) * 64;
  const int lm = lane & 15, lq = lane >> 4;
  const int pb = lm & 7;

  f32x4 acc[4][4] = {};

  int sm[4], skc[4], sub[4];
#pragma unroll
  for (int i = 0; i < 4; ++i) {
    const int u = i * 256 + t;
    sm[i] = u >> 3;
    skc[i] = (u & 7) ^ (sm[i] & 7);
    sub[i] = (i * 256 + w64) * 8;
  }

  const int nk = K >> 6;
  for (int kt = 0; kt < nk; ++kt) {
    const int k0 = kt << 6;
    __syncthreads();
#pragma unroll
    for (int i = 0; i < 4; ++i) {
      const size_t ga = (size_t)(row0 + sm[i]) * K + k0 + skc[i] * 8;
      const size_t gb = (size_t)(col0 + sm[i]) * K + k0 + skc[i] * 8;
      ld_lds16(Ahi + ga, &sAhi[sub[i]]);
      ld_lds16(Alo + ga, &sAlo[sub[i]]);
      ld_lds16(Bhi + gb, &sBhi[sub[i]]);
      ld_lds16(Blo + gb, &sBlo[sub[i]]);
    }
    __syncthreads();
#pragma unroll
    for (int kk = 0; kk < 2; ++kk) {
      const int pos = ((kk * 4 + lq) ^ pb) * 8;
      bf16x8 ah[4], al[4], bh[4], bl[4];
#pragma unroll
      for (int i = 0; i < 4; ++i) {
        const int ma = (wm + i * 16 + lm) * 64;
        const int mb = (wn + i * 16 + lm) * 64;
        ah[i] = *(const bf16x8*)&sAhi[ma + pos];
        al[i] = *(const bf16x8*)&sAlo[ma + pos];
        bh[i] = *(const bf16x8*)&sBhi[mb + pos];
        bl[i] = *(const bf16x8*)&sBlo[mb + pos];
      }
#pragma unroll
      for (int i = 0; i < 4; ++i)
#pragma unroll
        for (int j = 0; j < 4; ++j) {
          acc[i][j] = __builtin_amdgcn_mfma_f32_16x16x32_bf16(ah[i], bh[j], acc[i][j], 0, 0, 0);
          acc[i][j] = __builtin_amdgcn_mfma_f32_16x16x32_bf16(al[i], bh[j], acc[i][j], 0, 0, 0);
          acc[i][j] = __builtin_amdgcn_mfma_f32_16x16x32_bf16(ah[i], bl[j], acc[i][j], 0, 0, 0);
        }
    }
  }

#pragma unroll
  for (int i = 0; i < 4; ++i) {
    const int grow = row0 + wm + i * 16 + lq * 4;
#pragma unroll
    for (int j = 0; j < 4; ++j) {
      const int gcol = col0 + wn + j * 16 + lm;
      const float bs = bias ? bias[gcol] : 0.0f;
#pragma unroll
      for (int d = 0; d < 4; ++d) {
        const float v = acc[i][j][d] + bs;
        const size_t idx = (size_t)(grow + d) * N + gcol;
        C[idx] = v;
        if (SPLIT_OUT) {
          const float h = bf_val(v);
          Chi[idx] = bf_bits(v);
          Clo[idx] = bf_bits(v - h);
        }
      }
    }
  }
}

// ---------------- fused gh-GEMM + GRU gate kernel ----------------
// Tile: 128(M) x 96(N') per block, BK=32, 4 waves each 64x48 (= 16 h-cols x 3 gates).
// W' rows gate-interleaved so lane lm holds r/u/n for the same h-col in acc[i][0..2].
// LDS: sA = [hi 512 | lo 512] units of 8 u16 (row-major [128][32] each),
//      sB = [hi 384 | lo 384] units ([96][32] each). 28 KB total.
__global__ __launch_bounds__(256, 4) void k_fused(
    const u16* __restrict__ Ahi, const u16* __restrict__ Alo,   // h splits [4096][1024]
    const u16* __restrict__ Bhi, const u16* __restrict__ Blo,   // Whh' splits [3072][1024]
    const float* __restrict__ C0,                               // [4096][3072] W'-order
    const float* __restrict__ token,                            // [4096][4]
    const float* __restrict__ wtok,                             // [3072][3] W'-order
    const float* __restrict__ b_hh,                             // original [3072]
    const float* __restrict__ h_in, float* __restrict__ h_out,
    u16* __restrict__ ho_hi, u16* __restrict__ ho_lo) {
  const int K = HIDN;
  __shared__ __align__(16) u16 sA[1024 * 8];
  __shared__ __align__(16) u16 sB[768 * 8];

  const int t = threadIdx.x;
  const int wave = t >> 6, lane = t & 63;
  const int w64 = wave * 64;
  const int row0 = blockIdx.y * 128;
  const int colW0 = blockIdx.x * 96;
  const int wm = (wave & 1) * 64;
  const int wn = (wave >> 1) * 48;
  const int lm = lane & 15, lq = lane >> 4;

  f32x4 acc[4][3] = {};

  for (int kt = 0; kt < 32; ++kt) {
    const int k0 = kt << 5;
    __syncthreads();
#pragma unroll
    for (int i = 0; i < 4; ++i) {
      const int ub = i * 256 + w64;          // wave-uniform
      const int u = ub + lane;
      const u16* src = (ub < 512) ? Ahi : Alo;
      const int uu = u & 511;
      ld_lds16(src + (size_t)(row0 + (uu >> 2)) * K + k0 + (uu & 3) * 8, &sA[u * 8]);
    }
#pragma unroll
    for (int i = 0; i < 3; ++i) {
      const int ub = i * 256 + w64;          // wave-uniform; 384 boundary is wave-aligned
      const int u = ub + lane;
      const u16* src = (ub < 384) ? Bhi : Blo;
      const int uu = (ub < 384) ? u : (u - 384);
      ld_lds16(src + (size_t)(colW0 + (uu >> 2)) * K + k0 + (uu & 3) * 8, &sB[u * 8]);
    }
    __syncthreads();
    bf16x8 ah[4], al[4], bh[3], bl[3];
#pragma unroll
    for (int i = 0; i < 4; ++i) {
      const int o = (wm + i * 16 + lm) * 32 + lq * 8;
      ah[i] = *(const bf16x8*)&sA[o];
      al[i] = *(const bf16x8*)&sA[o + 4096];
    }
#pragma unroll
    for (int j = 0; j < 3; ++j) {
      const int o = (wn + j * 16 + lm) * 32 + lq * 8;
      bh[j] = *(const bf16x8*)&sB[o];
      bl[j] = *(const bf16x8*)&sB[o + 3072];
    }
#pragma unroll
    for (int i = 0; i < 4; ++i)
#pragma unroll
      for (int j = 0; j < 3; ++j) {
        acc[i][j] = __builtin_amdgcn_mfma_f32_16x16x32_bf16(ah[i], bh[j], acc[i][j], 0, 0, 0);
        acc[i][j] = __builtin_amdgcn_mfma_f32_16x16x32_bf16(al[i], bh[j], acc[i][j], 0, 0, 0);
        acc[i][j] = __builtin_amdgcn_mfma_f32_16x16x32_bf16(ah[i], bl[j], acc[i][j], 0, 0, 0);
      }
  }

  // ---- fused GRU epilogue (exact f32) ----
  const int c = blockIdx.x * 32 + (wave >> 1) * 16 + lm;  // h-col
  const int w0 = colW0 + wn + lm;                          // W'-row of r-gate
  float wt[3][3];
#pragma unroll
  for (int j = 0; j < 3; ++j) {
    wt[j][0] = wtok[(w0 + j * 16) * 3 + 0];
    wt[j][1] = wtok[(w0 + j * 16) * 3 + 1];
    wt[j][2] = wtok[(w0 + j * 16) * 3 + 2];
  }
  const float bn = b_hh[2048 + c];
#pragma unroll
  for (int i = 0; i < 4; ++i) {
#pragma unroll
    for (int d = 0; d < 4; ++d) {
      const int row = row0 + wm + i * 16 + lq * 4 + d;
      const float4 tk = *(const float4*)&token[row * 4];
      const size_t cb = (size_t)row * NP;
      const float pr = C0[cb + w0] + acc[i][0][d] + tk.x * wt[0][0] + tk.y * wt[0][1] + tk.z * wt[0][2];
      const float pu = C0[cb + w0 + 16] + acc[i][1][d] + tk.x * wt[1][0] + tk.y * wt[1][1] + tk.z * wt[1][2];
      const float pn = C0[cb + w0 + 32] + tk.x * wt[2][0] + tk.y * wt[2][1] + tk.z * wt[2][2];
      const float hn = acc[i][2][d] + bn;
      const float r = 1.0f / (1.0f + expf(-pr));
      const float u = 1.0f / (1.0f + expf(-pu));
      const float n = tanhf(pn + r * hn);
      const size_t hidx = (size_t)row * HIDN + c;
      const float ho = h_in[hidx];
      const float hv = (1.0f - u) * n + u * ho;
      h_out[hidx] = hv;
      const float hh = bf_val(hv);
      ho_hi[hidx] = bf_bits(hv);
      ho_lo[hidx] = bf_bits(hv - hh);
    }
  }
}

// ---------------- per-step output kernel ----------------
__global__ __launch_bounds__(256) void k_out(
    const float* __restrict__ h, const float* __restrict__ W_out,
    const float* __restrict__ b_out,
    float* __restrict__ out, float* __restrict__ token, int step) {
  const int wave = threadIdx.x >> 6, lane = threadIdx.x & 63;
  const int row = blockIdx.x * 4 + wave;
  const float4* hp = (const float4*)(h + (size_t)row * 1024);
  const float4* w0p = (const float4*)(W_out);
  const float4* w1p = (const float4*)(W_out + 1024);
  const float4* w2p = (const float4*)(W_out + 2048);
  float s0 = 0.f, s1 = 0.f, s2 = 0.f;
#pragma unroll
  for (int c = 0; c < 4; ++c) {
    const int k = lane + 64 * c;
    const float4 hv = hp[k];
    const float4 a = w0p[k], bq = w1p[k], cq = w2p[k];
    s0 += hv.x * a.x + hv.y * a.y + hv.z * a.z + hv.w * a.w;
    s1 += hv.x * bq.x + hv.y * bq.y + hv.z * bq.z + hv.w * bq.w;
    s2 += hv.x * cq.x + hv.y * cq.y + hv.z * cq.z + hv.w * cq.w;
  }
#pragma unroll
  for (int off = 32; off > 0; off >>= 1) {
    s0 += __shfl_xor(s0, off, 64);
    s1 += __shfl_xor(s1, off, 64);
    s2 += __shfl_xor(s2, off, 64);
  }
  if (lane == 0) {
    const float o0 = s0 + b_out[0];
    const float o1 = s1 + b_out[1];
    const float o2 = s2 + b_out[2];
    const float bass = 1.0f / (1.0f + expf(-o0));
    const float rhy = 1.0f / (1.0f + expf(-o2));
    const size_t ob = ((size_t)row * NST + step) * 3;
    out[ob + 0] = bass;
    out[ob + 1] = o1;
    out[ob + 2] = rhy;
    token[row * 4 + 0] = bass;
    token[row * 4 + 1] = o1;
    token[row * 4 + 2] = (rhy > 0.5f) ? 1.0f : 0.0f;
  }
}

// ---------------- host ----------------
extern "C" void kernel_launch(void* const* d_in, const int* in_sizes, int n_in,
                              void* d_out, int out_size, void* d_ws, size_t ws_size,
                              hipStream_t stream) {
  const float* z = (const float*)d_in[0];
  const float* W_zh = (const float*)d_in[3];
  const float* b_zh = (const float*)d_in[4];
  const float* W_zi = (const float*)d_in[5];
  const float* b_zi = (const float*)d_in[6];
  const float* W_ih = (const float*)d_in[7];
  const float* b_ih = (const float*)d_in[8];
  const float* W_hh = (const float*)d_in[9];
  const float* b_hh = (const float*)d_in[10];
  const float* W_out = (const float*)d_in[11];
  const float* b_out = (const float*)d_in[12];
  const float* init_input = (const float*)d_in[13];
  float* out = (float*)d_out;

  char* p = (char*)d_ws;
  auto alloc = [&](size_t bytes) {
    char* q = p;
    p += (bytes + 255) & ~(size_t)255;
    return q;
  };
  float* h[2];
  u16 *h_hi[2], *h_lo[2];
  for (int s = 0; s < 2; ++s) {
    h[s] = (float*)alloc((size_t)BS * HIDN * 4);
    h_hi[s] = (u16*)alloc((size_t)BS * HIDN * 2);
    h_lo[s] = (u16*)alloc((size_t)BS * HIDN * 2);
  }
  float* C0 = (float*)alloc((size_t)BS * NP * 4);
  u16* z_hi = (u16*)alloc((size_t)BS * ZD * 2);
  u16* z_lo = (u16*)alloc((size_t)BS * ZD * 2);
  float* zin = (float*)alloc((size_t)BS * ZINN * 4);
  u16* zin_hi = (u16*)alloc((size_t)BS * ZINN * 2);
  u16* zin_lo = (u16*)alloc((size_t)BS * ZINN * 2);
  u16* Wzh_hi = (u16*)alloc((size_t)HIDN * ZD * 2);
  u16* Wzh_lo = (u16*)alloc((size_t)HIDN * ZD * 2);
  u16* Wzi_hi = (u16*)alloc((size_t)ZINN * ZD * 2);
  u16* Wzi_lo = (u16*)alloc((size_t)ZINN * ZD * 2);
  u16* Wihz_hi = (u16*)alloc((size_t)NP * ZINN * 2);
  u16* Wihz_lo = (u16*)alloc((size_t)NP * ZINN * 2);
  u16* Whh_hi = (u16*)alloc((size_t)NP * HIDN * 2);
  u16* Whh_lo = (u16*)alloc((size_t)NP * HIDN * 2);
  float* wtok = (float*)alloc((size_t)NP * 3 * 4);
  float* cb0 = (float*)alloc((size_t)NP * 4);
  float* token = (float*)alloc((size_t)BS * 4 * 4);

  // ---- prep ----
  k_split_whh<<<dim3((NP * HIDN + 255) / 256), 256, 0, stream>>>(W_hh, Whh_hi, Whh_lo);
  k_split<<<dim3((HIDN * ZD + 255) / 256), 256, 0, stream>>>(W_zh, Wzh_hi, Wzh_lo, HIDN * ZD);
  k_split<<<dim3((ZINN * ZD + 255) / 256), 256, 0, stream>>>(W_zi, Wzi_hi, Wzi_lo, ZINN * ZD);
  k_split<<<dim3((BS * ZD + 255) / 256), 256, 0, stream>>>(z, z_hi, z_lo, BS * ZD);
  k_prep_wih<<<dim3((NP * 128 + 255) / 256), 256, 0, stream>>>(W_ih, b_ih, b_hh, Wihz_hi, Wihz_lo, wtok, cb0);
  k_token_init<<<dim3((BS * 4 + 255) / 256), 256, 0, stream>>>(init_input, token);

  // ---- prep GEMMs ----
  // h0 = z @ W_zh^T + b_zh -> ping-pong slot 0 (f32 + splits)
  k_gemm<true><<<dim3(HIDN / 128, BS / 128), 256, 0, stream>>>(
      z_hi, z_lo, Wzh_hi, Wzh_lo, b_zh, h[0], h_hi[0], h_lo[0], HIDN, ZD);
  // z_in = z @ W_zi^T + b_zi
  k_gemm<true><<<dim3(ZINN / 128, BS / 128), 256, 0, stream>>>(
      z_hi, z_lo, Wzi_hi, Wzi_lo, b_zi, zin, zin_hi, zin_lo, ZINN, ZD);
  // C0 = z_in @ Wihz'^T + cb0'   (W'-ordered columns)
  k_gemm<false><<<dim3(NP / 128, BS / 128), 256, 0, stream>>>(
      zin_hi, zin_lo, Wihz_hi, Wihz_lo, cb0, C0, nullptr, nullptr, NP, ZINN);

  // ---- 32 recurrent steps ----
  for (int t = 0; t < NST; ++t) {
    const int cur = t & 1, nxt = (t + 1) & 1;
    k_fused<<<dim3(NP / 96, BS / 128), 256, 0, stream>>>(
        h_hi[cur], h_lo[cur], Whh_hi, Whh_lo, C0, token, wtok, b_hh,
        h[cur], h[nxt], h_hi[nxt], h_lo[nxt]);
    k_out<<<dim3(BS / 4), 256, 0, stream>>>(h[nxt], W_out, b_out, out, token, t);
  }
  (void)in_sizes; (void)n_in; (void)out_size; (void)ws_size;
}

// Round 4
// 2697.351 us; speedup vs baseline: 1.5392x; 1.1809x over previous
//
#include <hip/hip_runtime.h>
#include <hip/hip_bf16.h>
#include <math.h>

#define BS   4096
#define ZD   512
#define HIDN 1024
#define ZINN 128
#define NST  32
#define NP   3072   // 3*HIDN, gate-interleaved column space

typedef unsigned short u16;
typedef __bf16 bf16x8 __attribute__((ext_vector_type(8)));
typedef float f32x4 __attribute__((ext_vector_type(4)));

static __device__ __forceinline__ u16 bf_bits(float v) {
  __bf16 b = (__bf16)v;
  return __builtin_bit_cast(unsigned short, b);
}
static __device__ __forceinline__ float bf_val(float v) {
  return (float)(__bf16)v;
}

// async global -> LDS, 16 bytes per lane. LDS dest = wave-uniform base + lane*16.
static __device__ __forceinline__ void ld_lds16(const u16* g, u16* l) {
  __builtin_amdgcn_global_load_lds(
      (const __attribute__((address_space(1))) void*)g,
      (__attribute__((address_space(3))) void*)l, 16, 0, 0);
}

// W' row w -> original W_hh/W_ih row. w = g*48 + j*16 + m  ->  j*1024 + g*16 + m
static __device__ __forceinline__ int r_orig(int w) {
  const int g = w / 48;
  const int rem = w - g * 48;
  const int j = rem >> 4, m = rem & 15;
  return j * 1024 + g * 16 + m;
}

// ---------------- prep kernels ----------------

__global__ void k_split(const float* __restrict__ s, u16* __restrict__ hi,
                        u16* __restrict__ lo, int n) {
  int i = blockIdx.x * 256 + threadIdx.x;
  if (i >= n) return;
  float v = s[i];
  float h = bf_val(v);
  hi[i] = bf_bits(v);
  lo[i] = bf_bits(v - h);
}

// W_hh split with gate-interleaved row reorder
__global__ void k_split_whh(const float* __restrict__ W_hh, u16* __restrict__ hi,
                            u16* __restrict__ lo) {
  int i = blockIdx.x * 256 + threadIdx.x;
  if (i >= NP * HIDN) return;
  const int w = i >> 10, k = i & 1023;
  const float v = W_hh[(size_t)r_orig(w) * HIDN + k];
  const float h = bf_val(v);
  hi[i] = bf_bits(v);
  lo[i] = bf_bits(v - h);
}

// W_ih[:,3:131] -> split (reordered rows); W_ih[:,0:3] -> wtok (reordered); cb0 (reordered)
__global__ void k_prep_wih(const float* __restrict__ W_ih, const float* __restrict__ b_ih,
                           const float* __restrict__ b_hh,
                           u16* __restrict__ whi, u16* __restrict__ wlo,
                           float* __restrict__ wtok, float* __restrict__ cb0) {
  int i = blockIdx.x * 256 + threadIdx.x;
  if (i < NP * 128) {
    const int w = i >> 7, c = i & 127;
    const int r = r_orig(w);
    const float v = W_ih[r * 131 + 3 + c];
    const float h = bf_val(v);
    whi[i] = bf_bits(v);
    wlo[i] = bf_bits(v - h);
  }
  if (i < NP * 3) {
    const int w = i / 3, s = i - w * 3;
    wtok[i] = W_ih[r_orig(w) * 131 + s];
  }
  if (i < NP) {
    const int r = r_orig(i);
    cb0[i] = b_ih[r] + (r < 2048 ? b_hh[r] : 0.0f);
  }
}

__global__ void k_token_init(const float* __restrict__ init_input, float* __restrict__ token) {
  int i = blockIdx.x * 256 + threadIdx.x;
  if (i < BS * 4) token[i] = ((i & 3) < 3) ? init_input[i & 3] : 0.0f;
}

// ---------------- generic split-3 GEMM (prep only): C = A*B^T (+bias) ----------------
template <bool SPLIT_OUT>
__global__ __launch_bounds__(256) void k_gemm(
    const u16* __restrict__ Ahi, const u16* __restrict__ Alo,
    const u16* __restrict__ Bhi, const u16* __restrict__ Blo,
    const float* __restrict__ bias,
    float* __restrict__ C, u16* __restrict__ Chi, u16* __restrict__ Clo,
    int N, int K) {
  __shared__ __align__(16) u16 sAhi[128 * 64];
  __shared__ __align__(16) u16 sAlo[128 * 64];
  __shared__ __align__(16) u16 sBhi[128 * 64];
  __shared__ __align__(16) u16 sBlo[128 * 64];

  const int t = threadIdx.x;
  const int row0 = blockIdx.y * 128, col0 = blockIdx.x * 128;
  const int wave = t >> 6, lane = t & 63;
  const int w64 = wave * 64;
  const int wm = (wave & 1) * 64, wn = (wave >> 1) * 64;
  const int lm = lane & 15, lq = lane >> 4;
  const int pb = lm & 7;

  f32x4 acc[4][4] = {};

  int sm[4], skc[4], sub[4];
#pragma unroll
  for (int i = 0; i < 4; ++i) {
    const int u = i * 256 + t;
    sm[i] = u >> 3;
    skc[i] = (u & 7) ^ (sm[i] & 7);
    sub[i] = (i * 256 + w64) * 8;
  }

  const int nk = K >> 6;
  for (int kt = 0; kt < nk; ++kt) {
    const int k0 = kt << 6;
    __syncthreads();
#pragma unroll
    for (int i = 0; i < 4; ++i) {
      const size_t ga = (size_t)(row0 + sm[i]) * K + k0 + skc[i] * 8;
      const size_t gb = (size_t)(col0 + sm[i]) * K + k0 + skc[i] * 8;
      ld_lds16(Ahi + ga, &sAhi[sub[i]]);
      ld_lds16(Alo + ga, &sAlo[sub[i]]);
      ld_lds16(Bhi + gb, &sBhi[sub[i]]);
      ld_lds16(Blo + gb, &sBlo[sub[i]]);
    }
    __syncthreads();
#pragma unroll
    for (int kk = 0; kk < 2; ++kk) {
      const int pos = ((kk * 4 + lq) ^ pb) * 8;
      bf16x8 ah[4], al[4], bh[4], bl[4];
#pragma unroll
      for (int i = 0; i < 4; ++i) {
        const int ma = (wm + i * 16 + lm) * 64;
        const int mb = (wn + i * 16 + lm) * 64;
        ah[i] = *(const bf16x8*)&sAhi[ma + pos];
        al[i] = *(const bf16x8*)&sAlo[ma + pos];
        bh[i] = *(const bf16x8*)&sBhi[mb + pos];
        bl[i] = *(const bf16x8*)&sBlo[mb + pos];
      }
#pragma unroll
      for (int i = 0; i < 4; ++i)
#pragma unroll
        for (int j = 0; j < 4; ++j) {
          acc[i][j] = __builtin_amdgcn_mfma_f32_16x16x32_bf16(ah[i], bh[j], acc[i][j], 0, 0, 0);
          acc[i][j] = __builtin_amdgcn_mfma_f32_16x16x32_bf16(al[i], bh[j], acc[i][j], 0, 0, 0);
          acc[i][j] = __builtin_amdgcn_mfma_f32_16x16x32_bf16(ah[i], bl[j], acc[i][j], 0, 0, 0);
        }
    }
  }

#pragma unroll
  for (int i = 0; i < 4; ++i) {
    const int grow = row0 + wm + i * 16 + lq * 4;
#pragma unroll
    for (int j = 0; j < 4; ++j) {
      const int gcol = col0 + wn + j * 16 + lm;
      const float bs = bias ? bias[gcol] : 0.0f;
#pragma unroll
      for (int d = 0; d < 4; ++d) {
        const float v = acc[i][j][d] + bs;
        const size_t idx = (size_t)(grow + d) * N + gcol;
        C[idx] = v;
        if (SPLIT_OUT) {
          const float h = bf_val(v);
          Chi[idx] = bf_bits(v);
          Clo[idx] = bf_bits(v - h);
        }
      }
    }
  }
}

// ---------------- fused gh-GEMM + GRU gate kernel (v2) ----------------
// Block tile 128(M) x 192(N'), BK=64, 4 waves each 64x96 (acc[4][6]).
// LDS 80 KB -> 2 blocks/CU; XOR-swizzled chunks (c stored at c^(row&7)) keep
// both the global_load_lds staging (lane-contiguous) and the ds_read_b128
// fragment reads (2-way max) conflict-free.
__global__ __launch_bounds__(256, 2) void k_fused(
    const u16* __restrict__ Ahi, const u16* __restrict__ Alo,   // h splits [4096][1024]
    const u16* __restrict__ Bhi, const u16* __restrict__ Blo,   // Whh' splits [3072][1024]
    const float* __restrict__ C0,                               // [4096][3072] W'-order
    const float* __restrict__ token,                            // [4096][4]
    const float* __restrict__ wtok,                             // [3072][3] W'-order
    const float* __restrict__ b_hh,                             // original [3072]
    const float* __restrict__ h_in, float* __restrict__ h_out,
    u16* __restrict__ ho_hi, u16* __restrict__ ho_lo) {
  const int K = HIDN;
  __shared__ __align__(16) u16 sAhi[128 * 64];
  __shared__ __align__(16) u16 sAlo[128 * 64];
  __shared__ __align__(16) u16 sBhi[192 * 64];
  __shared__ __align__(16) u16 sBlo[192 * 64];

  const int t = threadIdx.x;
  const int wave = t >> 6, lane = t & 63;
  const int w64 = wave * 64;
  const int row0 = blockIdx.y * 128;
  const int colW0 = blockIdx.x * 192;
  const int wm = (wave & 1) * 64;
  const int wn = (wave >> 1) * 96;
  const int lm = lane & 15, lq = lane >> 4;
  const int pb = lm & 7;

  f32x4 acc[4][6] = {};

  // staging decomposition (XOR-swizzled chunk positions)
  int aoff[4], aub[4], boff[6], bub[6];
#pragma unroll
  for (int i = 0; i < 4; ++i) {
    const int u = i * 256 + t;
    const int r = u >> 3;
    const int kc = (u & 7) ^ (r & 7);
    aoff[i] = (row0 + r) * K + kc * 8;
    aub[i] = (i * 256 + w64) * 8;
  }
#pragma unroll
  for (int i = 0; i < 6; ++i) {
    const int u = i * 256 + t;
    const int r = u >> 3;
    const int kc = (u & 7) ^ (r & 7);
    boff[i] = (colW0 + r) * K + kc * 8;
    bub[i] = (i * 256 + w64) * 8;
  }

  for (int kt = 0; kt < 16; ++kt) {
    const int k0 = kt << 6;
    __syncthreads();
#pragma unroll
    for (int i = 0; i < 4; ++i) {
      ld_lds16(Ahi + aoff[i] + k0, &sAhi[aub[i]]);
      ld_lds16(Alo + aoff[i] + k0, &sAlo[aub[i]]);
    }
#pragma unroll
    for (int i = 0; i < 6; ++i) {
      ld_lds16(Bhi + boff[i] + k0, &sBhi[bub[i]]);
      ld_lds16(Blo + boff[i] + k0, &sBlo[bub[i]]);
    }
    __syncthreads();
#pragma unroll
    for (int kk = 0; kk < 2; ++kk) {
      const int pos = ((kk * 4 + lq) ^ pb) * 8;
      bf16x8 ah[4], al[4], bh[6], bl[6];
#pragma unroll
      for (int i = 0; i < 4; ++i) {
        const int ma = (wm + i * 16 + lm) * 64;
        ah[i] = *(const bf16x8*)&sAhi[ma + pos];
        al[i] = *(const bf16x8*)&sAlo[ma + pos];
      }
#pragma unroll
      for (int j = 0; j < 6; ++j) {
        const int mb = (wn + j * 16 + lm) * 64;
        bh[j] = *(const bf16x8*)&sBhi[mb + pos];
        bl[j] = *(const bf16x8*)&sBlo[mb + pos];
      }
#pragma unroll
      for (int i = 0; i < 4; ++i)
#pragma unroll
        for (int j = 0; j < 6; ++j) {
          acc[i][j] = __builtin_amdgcn_mfma_f32_16x16x32_bf16(ah[i], bh[j], acc[i][j], 0, 0, 0);
          acc[i][j] = __builtin_amdgcn_mfma_f32_16x16x32_bf16(al[i], bh[j], acc[i][j], 0, 0, 0);
          acc[i][j] = __builtin_amdgcn_mfma_f32_16x16x32_bf16(ah[i], bl[j], acc[i][j], 0, 0, 0);
        }
    }
  }

  // ---- fused GRU epilogue (exact f32); two gate-triples per wave (jt=0,1) ----
#pragma unroll
  for (int jt = 0; jt < 2; ++jt) {
    const int w0 = colW0 + wn + jt * 48 + lm;   // W'-row of r-gate
    const int g = (colW0 + wn + jt * 48) / 48;  // h-col group
    const int c = g * 16 + lm;                  // h-col
    float wt[3][3];
#pragma unroll
    for (int j = 0; j < 3; ++j) {
      wt[j][0] = wtok[(w0 + j * 16) * 3 + 0];
      wt[j][1] = wtok[(w0 + j * 16) * 3 + 1];
      wt[j][2] = wtok[(w0 + j * 16) * 3 + 2];
    }
    const float bn = b_hh[2048 + c];
#pragma unroll
    for (int i = 0; i < 4; ++i) {
#pragma unroll
      for (int d = 0; d < 4; ++d) {
        const int row = row0 + wm + i * 16 + lq * 4 + d;
        const float4 tk = *(const float4*)&token[row * 4];
        const size_t cb = (size_t)row * NP;
        const float pr = C0[cb + w0] + acc[i][jt * 3 + 0][d] + tk.x * wt[0][0] + tk.y * wt[0][1] + tk.z * wt[0][2];
        const float pu = C0[cb + w0 + 16] + acc[i][jt * 3 + 1][d] + tk.x * wt[1][0] + tk.y * wt[1][1] + tk.z * wt[1][2];
        const float pn = C0[cb + w0 + 32] + tk.x * wt[2][0] + tk.y * wt[2][1] + tk.z * wt[2][2];
        const float hn = acc[i][jt * 3 + 2][d] + bn;
        const float r = 1.0f / (1.0f + expf(-pr));
        const float u = 1.0f / (1.0f + expf(-pu));
        const float n = tanhf(pn + r * hn);
        const size_t hidx = (size_t)row * HIDN + c;
        const float ho = h_in[hidx];
        const float hv = (1.0f - u) * n + u * ho;
        h_out[hidx] = hv;
        const float hh = bf_val(hv);
        ho_hi[hidx] = bf_bits(hv);
        ho_lo[hidx] = bf_bits(hv - hh);
      }
    }
  }
}

// ---------------- per-step output kernel ----------------
__global__ __launch_bounds__(256) void k_out(
    const float* __restrict__ h, const float* __restrict__ W_out,
    const float* __restrict__ b_out,
    float* __restrict__ out, float* __restrict__ token, int step) {
  const int wave = threadIdx.x >> 6, lane = threadIdx.x & 63;
  const int row = blockIdx.x * 4 + wave;
  const float4* hp = (const float4*)(h + (size_t)row * 1024);
  const float4* w0p = (const float4*)(W_out);
  const float4* w1p = (const float4*)(W_out + 1024);
  const float4* w2p = (const float4*)(W_out + 2048);
  float s0 = 0.f, s1 = 0.f, s2 = 0.f;
#pragma unroll
  for (int c = 0; c < 4; ++c) {
    const int k = lane + 64 * c;
    const float4 hv = hp[k];
    const float4 a = w0p[k], bq = w1p[k], cq = w2p[k];
    s0 += hv.x * a.x + hv.y * a.y + hv.z * a.z + hv.w * a.w;
    s1 += hv.x * bq.x + hv.y * bq.y + hv.z * bq.z + hv.w * bq.w;
    s2 += hv.x * cq.x + hv.y * cq.y + hv.z * cq.z + hv.w * cq.w;
  }
#pragma unroll
  for (int off = 32; off > 0; off >>= 1) {
    s0 += __shfl_xor(s0, off, 64);
    s1 += __shfl_xor(s1, off, 64);
    s2 += __shfl_xor(s2, off, 64);
  }
  if (lane == 0) {
    const float o0 = s0 + b_out[0];
    const float o1 = s1 + b_out[1];
    const float o2 = s2 + b_out[2];
    const float bass = 1.0f / (1.0f + expf(-o0));
    const float rhy = 1.0f / (1.0f + expf(-o2));
    const size_t ob = ((size_t)row * NST + step) * 3;
    out[ob + 0] = bass;
    out[ob + 1] = o1;
    out[ob + 2] = rhy;
    token[row * 4 + 0] = bass;
    token[row * 4 + 1] = o1;
    token[row * 4 + 2] = (rhy > 0.5f) ? 1.0f : 0.0f;
  }
}

// ---------------- host ----------------
extern "C" void kernel_launch(void* const* d_in, const int* in_sizes, int n_in,
                              void* d_out, int out_size, void* d_ws, size_t ws_size,
                              hipStream_t stream) {
  const float* z = (const float*)d_in[0];
  const float* W_zh = (const float*)d_in[3];
  const float* b_zh = (const float*)d_in[4];
  const float* W_zi = (const float*)d_in[5];
  const float* b_zi = (const float*)d_in[6];
  const float* W_ih = (const float*)d_in[7];
  const float* b_ih = (const float*)d_in[8];
  const float* W_hh = (const float*)d_in[9];
  const float* b_hh = (const float*)d_in[10];
  const float* W_out = (const float*)d_in[11];
  const float* b_out = (const float*)d_in[12];
  const float* init_input = (const float*)d_in[13];
  float* out = (float*)d_out;

  char* p = (char*)d_ws;
  auto alloc = [&](size_t bytes) {
    char* q = p;
    p += (bytes + 255) & ~(size_t)255;
    return q;
  };
  float* h[2];
  u16 *h_hi[2], *h_lo[2];
  for (int s = 0; s < 2; ++s) {
    h[s] = (float*)alloc((size_t)BS * HIDN * 4);
    h_hi[s] = (u16*)alloc((size_t)BS * HIDN * 2);
    h_lo[s] = (u16*)alloc((size_t)BS * HIDN * 2);
  }
  float* C0 = (float*)alloc((size_t)BS * NP * 4);
  u16* z_hi = (u16*)alloc((size_t)BS * ZD * 2);
  u16* z_lo = (u16*)alloc((size_t)BS * ZD * 2);
  float* zin = (float*)alloc((size_t)BS * ZINN * 4);
  u16* zin_hi = (u16*)alloc((size_t)BS * ZINN * 2);
  u16* zin_lo = (u16*)alloc((size_t)BS * ZINN * 2);
  u16* Wzh_hi = (u16*)alloc((size_t)HIDN * ZD * 2);
  u16* Wzh_lo = (u16*)alloc((size_t)HIDN * ZD * 2);
  u16* Wzi_hi = (u16*)alloc((size_t)ZINN * ZD * 2);
  u16* Wzi_lo = (u16*)alloc((size_t)ZINN * ZD * 2);
  u16* Wihz_hi = (u16*)alloc((size_t)NP * ZINN * 2);
  u16* Wihz_lo = (u16*)alloc((size_t)NP * ZINN * 2);
  u16* Whh_hi = (u16*)alloc((size_t)NP * HIDN * 2);
  u16* Whh_lo = (u16*)alloc((size_t)NP * HIDN * 2);
  float* wtok = (float*)alloc((size_t)NP * 3 * 4);
  float* cb0 = (float*)alloc((size_t)NP * 4);
  float* token = (float*)alloc((size_t)BS * 4 * 4);

  // ---- prep ----
  k_split_whh<<<dim3((NP * HIDN + 255) / 256), 256, 0, stream>>>(W_hh, Whh_hi, Whh_lo);
  k_split<<<dim3((HIDN * ZD + 255) / 256), 256, 0, stream>>>(W_zh, Wzh_hi, Wzh_lo, HIDN * ZD);
  k_split<<<dim3((ZINN * ZD + 255) / 256), 256, 0, stream>>>(W_zi, Wzi_hi, Wzi_lo, ZINN * ZD);
  k_split<<<dim3((BS * ZD + 255) / 256), 256, 0, stream>>>(z, z_hi, z_lo, BS * ZD);
  k_prep_wih<<<dim3((NP * 128 + 255) / 256), 256, 0, stream>>>(W_ih, b_ih, b_hh, Wihz_hi, Wihz_lo, wtok, cb0);
  k_token_init<<<dim3((BS * 4 + 255) / 256), 256, 0, stream>>>(init_input, token);

  // ---- prep GEMMs ----
  k_gemm<true><<<dim3(HIDN / 128, BS / 128), 256, 0, stream>>>(
      z_hi, z_lo, Wzh_hi, Wzh_lo, b_zh, h[0], h_hi[0], h_lo[0], HIDN, ZD);
  k_gemm<true><<<dim3(ZINN / 128, BS / 128), 256, 0, stream>>>(
      z_hi, z_lo, Wzi_hi, Wzi_lo, b_zi, zin, zin_hi, zin_lo, ZINN, ZD);
  k_gemm<false><<<dim3(NP / 128, BS / 128), 256, 0, stream>>>(
      zin_hi, zin_lo, Wihz_hi, Wihz_lo, cb0, C0, nullptr, nullptr, NP, ZINN);

  // ---- 32 recurrent steps ----
  for (int t = 0; t < NST; ++t) {
    const int cur = t & 1, nxt = (t + 1) & 1;
    k_fused<<<dim3(NP / 192, BS / 128), 256, 0, stream>>>(
        h_hi[cur], h_lo[cur], Whh_hi, Whh_lo, C0, token, wtok, b_hh,
        h[cur], h[nxt], h_hi[nxt], h_lo[nxt]);
    k_out<<<dim3(BS / 4), 256, 0, stream>>>(h[nxt], W_out, b_out, out, token, t);
  }
  (void)in_sizes; (void)n_in; (void)out_size; (void)ws_size;
}